// Round 9
// baseline (298.875 us; speedup 1.0000x reference)
//
#include <hip/hip_runtime.h>
#include <hip/hip_bf16.h>
#include <hip/hip_cooperative_groups.h>

namespace cg = cooperative_groups;

// Problem constants (RecurrentGCN / A3TGCN reduction)
constexpr int N_NODES = 20000;
constexpr int P_PER   = 12;
constexpr int N_EDGES = 640000;
constexpr int HID     = 100;

constexpr int BIN_W  = 64;                              // nodes per bin
constexpr int NB     = (N_NODES + BIN_W - 1) / BIN_W;   // 313 bins
constexpr int GRID   = 512;                             // cooperative grid (26.8KB LDS -> 5 blk/CU >= 2 needed)
constexpr int TPB    = 256;
constexpr int PCHUNK = N_EDGES / GRID;                  // 1250 edges per partition block
constexpr int SCAP   = 20;    // slice capacity per (block,bin); lambda=4, P(ovfl)~2e-9/cell
constexpr int ECAP   = 2560;  // per-bin total; lambda=2048, sigma=45 -> 11 sigma
constexpr int Y_STR  = 16;    // y row stride (floats), 64B-aligned rows

// Workspace layout (4-byte elements)
constexpr size_t OFF_UZ    = 0;
constexpr size_t OFF_CZ    = OFF_UZ + HID;
constexpr size_t OFF_UH    = OFF_CZ + HID;
constexpr size_t OFF_CH    = OFF_UH + HID;
constexpr size_t OFF_PROBS = OFF_CH + HID;                       // 400..412
constexpr size_t OFF_COUNT = 416;                                // GRID*NB ints (641KB)
constexpr size_t OFF_Y     = OFF_COUNT + (size_t)GRID * NB;      // 160672 (byte off 642688, /16 ok)
constexpr size_t OFF_SEG   = OFF_Y + (size_t)N_NODES * Y_STR;    // 480672, GRID*NB*SCAP int2 (25.6MB)
// total ~27.6 MB

// ---------------------------------------------------------------------------
// One cooperative kernel, 3 phases separated by grid.sync():
//  p1 (all blocks): deterministic sliced partition (no atomics, no memset)
//  p2 (blocks<NB): per-bin LDS counting sort + dinv + y; block GRID-1: precompute
//  p3 (blocks<NB): gather from own LDS-resident sorted edges + fused epilogue
__global__ __launch_bounds__(TPB) void fused_kernel(
        const float* __restrict__ x, const int* __restrict__ ei, const float* __restrict__ ew,
        const float* __restrict__ Wz, const float* __restrict__ bz,
        const float* __restrict__ Wh, const float* __restrict__ bh,
        const float* __restrict__ Wlz, const float* __restrict__ blz,
        const float* __restrict__ Wlh, const float* __restrict__ blh,
        const float* __restrict__ att, const float* __restrict__ Wout,
        const float* __restrict__ bout, float* __restrict__ out,
        float* __restrict__ uzg, float* __restrict__ czg,
        float* __restrict__ uhg, float* __restrict__ chg, float* __restrict__ probsg,
        int* __restrict__ count, float* __restrict__ y, int2* __restrict__ seg) {
    cg::grid_group grid = cg::this_grid();

    __shared__ int   run[NB];          // p1 slice cursors (block-local)
    __shared__ int   scnt[GRID];       // p2 per-slice counts for this bin
    __shared__ int2  ent2[ECAP];       // p2/p3 node-sorted edges (persist across grid.sync)
    __shared__ int   nhist[BIN_W], nexcl[BIN_W], noff[BIN_W];
    __shared__ float sdinv[BIN_W];
    __shared__ float s_uz[HID], s_cz[HID], s_uh[HID], s_ch[HID], s_wo[HID];
    __shared__ float s_pr[P_PER];

    const int t   = threadIdx.x;
    const int blk = blockIdx.x;

    // ---------------- phase 1: deterministic sliced partition ----------------
    for (int b = t; b < NB; b += TPB) run[b] = 0;
    __syncthreads();
    {
        const int e0 = blk * PCHUNK;
        const int* __restrict__ dsts = ei + N_EDGES;
        for (int i = t; i < PCHUNK; i += TPB) {
            int d = dsts[e0 + i];
            int s = ei[e0 + i];
            float wt = ew[e0 + i];
            int j = d >> 6;
            int slot = atomicAdd(&run[j], 1);          // LDS atomic only
            if (slot < SCAP)
                seg[((size_t)j * GRID + blk) * SCAP + slot] =
                    make_int2(s | ((d & 63) << 16), __float_as_int(wt));
        }
    }
    __syncthreads();
    for (int b = t; b < NB; b += TPB) count[blk * NB + b] = min(run[b], SCAP);

    grid.sync();

    // ---------------- phase 2: per-bin sort + dinv + y; precompute on last block
    if (blk == GRID - 1) {
        // rank-1 collapse of (GCN weight @ Wl[:HID]) + softmax(att); H0=0 kills r-gate
        if (t < HID) {
            float suz = 0.f, scz = 0.f, suh = 0.f, sch = 0.f;
            for (int j = 0; j < HID; ++j) {
                float wlz = Wlz[j * HID + t];
                float wlh = Wlh[j * HID + t];
                suz += Wz[j] * wlz;
                scz += bz[j] * wlz;
                suh += Wh[j] * wlh;
                sch += bh[j] * wlh;
            }
            uzg[t] = suz;
            czg[t] = scz + blz[t];
            uhg[t] = suh;
            chg[t] = sch + blh[t];
        }
        if (t == 0) {
            float m = att[0];
            for (int p = 1; p < P_PER; ++p) m = fmaxf(m, att[p]);
            float e[P_PER];
            float s = 0.f;
            for (int p = 0; p < P_PER; ++p) { e[p] = __expf(att[p] - m); s += e[p]; }
            float inv = 1.0f / s;
            for (int p = 0; p < P_PER; ++p) probsg[p] = e[p] * inv;
        }
    } else if (blk < NB) {
        const int j = blk;
        for (int i = t; i < GRID; i += TPB) scnt[i] = count[i * NB + j];
        if (t < BIN_W) nhist[t] = 0;
        __syncthreads();
        // pass A: node histogram over this bin's slices
        for (int i = t; i < GRID; i += TPB) {
            int cnt = scnt[i];
            const int2* sp = seg + ((size_t)j * GRID + i) * SCAP;
            for (int k = 0; k < cnt; ++k) atomicAdd(&nhist[sp[k].x >> 16], 1);
        }
        __syncthreads();
        // exclusive scan over 64 node counts (wave 0)
        if (t < 64) {
            int v = nhist[t];
            int inc = v;
#pragma unroll
            for (int o = 1; o < 64; o <<= 1) {
                int u = __shfl_up(inc, o, 64);
                if (t >= o) inc += u;
            }
            nexcl[t] = inc - v;
            noff[t]  = inc - v;
        }
        __syncthreads();
        // pass B: scatter into node-sorted LDS order
        for (int i = t; i < GRID; i += TPB) {
            int cnt = scnt[i];
            const int2* sp = seg + ((size_t)j * GRID + i) * SCAP;
            for (int k = 0; k < cnt; ++k) {
                int2 e = sp[k];
                int dl = e.x >> 16;
                int p = atomicAdd(&noff[dl], 1);
                if (p < ECAP) ent2[p] = make_int2(e.x & 0xFFFF, e.y);
            }
        }
        __syncthreads();
        // wsum per node from sorted runs, 4 lanes/node (no atomics)
        {
            int nl = t >> 2, l = t & 3;
            int beg = nexcl[nl], len = nhist[nl];
            float s = 0.f;
            for (int q = beg + l; q < beg + len; q += 4) s += __int_as_float(ent2[q].y);
            s += __shfl_xor(s, 1, 64);
            s += __shfl_xor(s, 2, 64);
            if (l == 0) sdinv[nl] = rsqrtf(1.0f + s);
        }
        __syncthreads();
        // y = dinv * x (padded rows)
        int n0 = j * BIN_W;
        for (int i = t; i < BIN_W * P_PER; i += TPB) {
            int nl = i / P_PER, p = i - nl * P_PER;
            int n = n0 + nl;
            if (n < N_NODES) y[(size_t)n * Y_STR + p] = sdinv[nl] * x[(size_t)n * P_PER + p];
        }
    }

    grid.sync();

    // ---------------- phase 3: gather from own LDS ent2 + fused epilogue ----
    if (blk >= NB) return;
    if (t < HID) {
        s_uz[t] = uzg[t]; s_cz[t] = czg[t];
        s_uh[t] = uhg[t]; s_ch[t] = chg[t];
        s_wo[t] = Wout[t];
    }
    if (t < P_PER) s_pr[t] = probsg[t];
    __syncthreads();

    int nl = t >> 2;
    int l  = t & 3;
    int n  = blk * BIN_W + nl;
    if (n >= N_NODES) return;

    int beg = nexcl[nl], len = nhist[nl];
    float acc[P_PER];
#pragma unroll
    for (int p = 0; p < P_PER; ++p) acc[p] = 0.f;
    for (int q = beg + l; q < beg + len; q += 4) {
        int2 e = ent2[q];
        float wt = __int_as_float(e.y);
        const float4* yr = (const float4*)(y + (size_t)e.x * Y_STR);
        float4 y0 = yr[0], y1 = yr[1], y2 = yr[2];
        acc[0]  += wt * y0.x;  acc[1]  += wt * y0.y;
        acc[2]  += wt * y0.z;  acc[3]  += wt * y0.w;
        acc[4]  += wt * y1.x;  acc[5]  += wt * y1.y;
        acc[6]  += wt * y1.z;  acc[7]  += wt * y1.w;
        acc[8]  += wt * y2.x;  acc[9]  += wt * y2.y;
        acc[10] += wt * y2.z;  acc[11] += wt * y2.w;
    }
    // reduce across the 4-lane node group; all lanes end with full sums
#pragma unroll
    for (int off = 1; off <= 2; off <<= 1) {
#pragma unroll
        for (int p = 0; p < P_PER; ++p) acc[p] += __shfl_xor(acc[p], off, 64);
    }
    {
        float dn = sdinv[nl];
        const float4* yr = (const float4*)(y + (size_t)n * Y_STR);
        float4 y0 = yr[0], y1 = yr[1], y2 = yr[2];
        acc[0]  = dn * (acc[0]  + y0.x);  acc[1]  = dn * (acc[1]  + y0.y);
        acc[2]  = dn * (acc[2]  + y0.z);  acc[3]  = dn * (acc[3]  + y0.w);
        acc[4]  = dn * (acc[4]  + y1.x);  acc[5]  = dn * (acc[5]  + y1.y);
        acc[6]  = dn * (acc[6]  + y1.z);  acc[7]  = dn * (acc[7]  + y1.w);
        acc[8]  = dn * (acc[8]  + y2.x);  acc[9]  = dn * (acc[9]  + y2.y);
        acc[10] = dn * (acc[10] + y2.z);  acc[11] = dn * (acc[11] + y2.w);
    }
    float rk = 0.f;
    for (int k = l; k < HID; k += 4) {      // 25 iterations per lane, uniform
        float uzk = s_uz[k], czk = s_cz[k], uhk = s_uh[k], chk = s_ch[k];
        float a2 = 0.f;
#pragma unroll
        for (int p = 0; p < P_PER; ++p) {
            float av = acc[p];
            float vz = fminf(fmaxf(av * uzk + czk, -30.f), 30.f);
            float vh = fminf(fmaxf(av * uhk + chk, -15.f), 15.f);
            float ez  = __expf(vz);
            float e2h = __expf(2.0f * vh);
            float term = (e2h - 1.0f) / ((1.0f + ez) * (e2h + 1.0f));  // sigmoid(-vz)*tanh(vh)
            a2 += s_pr[p] * term;
        }
        rk += fmaxf(a2, 0.0f) * s_wo[k];
    }
    rk += __shfl_xor(rk, 1, 64);
    rk += __shfl_xor(rk, 2, 64);
    if (l == 0) out[n] = rk + bout[0];
}

extern "C" void kernel_launch(void* const* d_in, const int* in_sizes, int n_in,
                              void* d_out, int out_size, void* d_ws, size_t ws_size,
                              hipStream_t stream) {
    const float* x   = (const float*)d_in[0];
    const int*   ei  = (const int*)d_in[1];
    const float* ew  = (const float*)d_in[2];
    const float* Wz  = (const float*)d_in[3];
    const float* bz  = (const float*)d_in[4];
    // d_in[5], d_in[6]: W_r, b_r — dead (H0 = 0)
    const float* Wh  = (const float*)d_in[7];
    const float* bh  = (const float*)d_in[8];
    const float* Wlz = (const float*)d_in[9];
    const float* blz = (const float*)d_in[10];
    // d_in[11], d_in[12]: Wl_r, bl_r — dead
    const float* Wlh = (const float*)d_in[13];
    const float* blh = (const float*)d_in[14];
    const float* att = (const float*)d_in[15];
    const float* Wout = (const float*)d_in[16];
    const float* bout = (const float*)d_in[17];
    float* out = (float*)d_out;

    float* ws     = (float*)d_ws;
    float* uzg    = ws + OFF_UZ;
    float* czg    = ws + OFF_CZ;
    float* uhg    = ws + OFF_UH;
    float* chg    = ws + OFF_CH;
    float* probsg = ws + OFF_PROBS;
    int*   count  = (int*)(ws + OFF_COUNT);
    float* y      = ws + OFF_Y;
    int2*  seg    = (int2*)(ws + OFF_SEG);

    void* args[] = {
        (void*)&x, (void*)&ei, (void*)&ew,
        (void*)&Wz, (void*)&bz, (void*)&Wh, (void*)&bh,
        (void*)&Wlz, (void*)&blz, (void*)&Wlh, (void*)&blh,
        (void*)&att, (void*)&Wout, (void*)&bout, (void*)&out,
        (void*)&uzg, (void*)&czg, (void*)&uhg, (void*)&chg, (void*)&probsg,
        (void*)&count, (void*)&y, (void*)&seg
    };
    hipLaunchCooperativeKernel((const void*)fused_kernel, dim3(GRID), dim3(TPB),
                               args, 0, stream);
}

// Round 10
// 157.720 us; speedup vs baseline: 1.8950x; 1.8950x over previous
//
#include <hip/hip_runtime.h>
#include <hip/hip_bf16.h>

// Problem constants (RecurrentGCN / A3TGCN reduction)
constexpr int N_NODES = 20000;
constexpr int P_PER   = 12;
constexpr int N_EDGES = 640000;
constexpr int HID     = 100;

constexpr int BIN_W   = 64;                              // nodes per bin
constexpr int NB      = (N_NODES + BIN_W - 1) / BIN_W;   // 313 bins
constexpr int BCAP    = 2560;                  // per-bin capacity; mean 2048, sigma 45 -> 11 sigma
constexpr int NBLK2   = 320;                   // partition blocks
constexpr int CHUNK   = N_EDGES / NBLK2;       // 2000
constexpr int CUR_STR = 16;                    // cursor padded to one per 64B line
constexpr int Y_STR   = 16;                    // y row stride (floats), 64B-aligned rows

// Workspace layout (4-byte elements)
constexpr size_t OFF_DINV  = 0;                               // N floats
constexpr size_t OFF_UZ    = OFF_DINV + N_NODES;              // 20000
constexpr size_t OFF_CZ    = OFF_UZ + HID;
constexpr size_t OFF_UH    = OFF_CZ + HID;
constexpr size_t OFF_CH    = OFF_UH + HID;
constexpr size_t OFF_PROBS = OFF_CH + HID;                    // 20400..20412
constexpr size_t OFF_CUR   = 20416;                           // NB*CUR_STR ints
constexpr size_t OFF_Y     = OFF_CUR + (size_t)NB * CUR_STR;  // 25424 (16B-aligned), N*Y_STR
constexpr size_t OFF_SEG   = OFF_Y + (size_t)N_NODES * Y_STR; // 345424, NB*BCAP int2
constexpr size_t OFF_SEG2  = OFF_SEG + (size_t)NB * BCAP * 2; // 1947984, NB*BCAP int2 (node-sorted)
constexpr size_t OFF_ROW   = OFF_SEG2 + (size_t)NB * BCAP * 2;// 3550544, N int2 (start,len)
// total ~14.3 MB

// ---------------------------------------------------------------------------
// k1: tiny precompute — rank-1 collapse of (GCN weight @ Wl[:HID]) + softmax(att)
__global__ void precompute_kernel(const float* __restrict__ Wz, const float* __restrict__ bz,
                                  const float* __restrict__ Wh, const float* __restrict__ bh,
                                  const float* __restrict__ Wlz, const float* __restrict__ blz,
                                  const float* __restrict__ Wlh, const float* __restrict__ blh,
                                  const float* __restrict__ att,
                                  float* __restrict__ uz, float* __restrict__ cz,
                                  float* __restrict__ uh, float* __restrict__ ch,
                                  float* __restrict__ probs) {
    int t = threadIdx.x;
    if (t < HID) {
        float suz = 0.f, scz = 0.f, suh = 0.f, sch = 0.f;
        for (int j = 0; j < HID; ++j) {
            float wlz = Wlz[j * HID + t];   // only first HID rows of (2*HID,HID) matter (H0=0)
            float wlh = Wlh[j * HID + t];
            suz += Wz[j] * wlz;
            scz += bz[j] * wlz;
            suh += Wh[j] * wlh;
            sch += bh[j] * wlh;
        }
        uz[t] = suz;
        cz[t] = scz + blz[t];
        uh[t] = suh;
        ch[t] = sch + blh[t];
    }
    if (t == 0) {
        float m = att[0];
        for (int p = 1; p < P_PER; ++p) m = fmaxf(m, att[p]);
        float e[P_PER];
        float s = 0.f;
        for (int p = 0; p < P_PER; ++p) { e[p] = __expf(att[p] - m); s += e[p]; }
        float inv = 1.0f / s;
        for (int p = 0; p < P_PER; ++p) probs[p] = e[p] * inv;
    }
}

// k2: partition edges into NB bins of 64 dst-nodes (coarse counting sort).
// Entry: .x = src | (d_local<<16)  [src < 2^16 since N=20000], .y = weight bits.
__global__ __launch_bounds__(256) void partition_kernel(const int* __restrict__ ei,
                                                        const float* __restrict__ w,
                                                        int* __restrict__ cur,
                                                        int2* __restrict__ seg) {
    __shared__ int hist[NB];
    __shared__ int base[NB];
    __shared__ int run[NB];
    int t = threadIdx.x;
    for (int b = t; b < NB; b += 256) { hist[b] = 0; run[b] = 0; }
    __syncthreads();
    int e0 = blockIdx.x * CHUNK;
    const int* __restrict__ dsts = ei + N_EDGES;
    for (int i = t; i < CHUNK; i += 256) {
        int d = dsts[e0 + i];
        atomicAdd(&hist[d >> 6], 1);
    }
    __syncthreads();
    for (int b = t; b < NB; b += 256) {
        int h = hist[b];
        base[b] = (h > 0) ? atomicAdd(cur + (size_t)b * CUR_STR, h) : 0;
    }
    __syncthreads();
    for (int i = t; i < CHUNK; i += 256) {
        int s = ei[e0 + i];
        int d = dsts[e0 + i];
        float wt = w[e0 + i];
        int b = d >> 6;
        int pos = base[b] + atomicAdd(&run[b], 1);
        if (pos < BCAP)
            seg[(size_t)b * BCAP + pos] = make_int2(s | ((d & 63) << 16), __float_as_int(wt));
    }
}

// k3: per-bin counting sort to node order + wsum/dinv/y, all in LDS.
__global__ __launch_bounds__(256) void binsort_kernel(const int2* __restrict__ seg,
                                                      const int* __restrict__ cur,
                                                      const float* __restrict__ x,
                                                      float* __restrict__ dinv,
                                                      float* __restrict__ y,
                                                      int2* __restrict__ seg2,
                                                      int2* __restrict__ rowinfo) {
    __shared__ int2 ent[BCAP];       // staged raw entries (20KB)
    __shared__ int2 ent2[BCAP];      // node-sorted entries (20KB)
    __shared__ int  hist[BIN_W];
    __shared__ int  off[BIN_W];
    __shared__ int  excl[BIN_W];
    __shared__ float sdinv[BIN_W];
    int t = threadIdx.x;
    int b = blockIdx.x;
    if (t < BIN_W) hist[t] = 0;
    __syncthreads();
    int c = min(cur[(size_t)b * CUR_STR], BCAP);
    const int2* sg = seg + (size_t)b * BCAP;
    for (int i = t; i < c; i += 256) {
        int2 e = sg[i];
        ent[i] = e;
        atomicAdd(&hist[e.x >> 16], 1);
    }
    __syncthreads();
    // exclusive prefix over 64 counters (wave 0 only, wave64 shuffle scan)
    if (t < 64) {
        int v = hist[t];
        int inc = v;
#pragma unroll
        for (int o = 1; o < 64; o <<= 1) {
            int u = __shfl_up(inc, o, 64);
            if (t >= o) inc += u;
        }
        int ex = inc - v;
        excl[t] = ex;
        off[t]  = ex;
    }
    __syncthreads();
    // scatter into node-sorted order (LDS)
    for (int i = t; i < c; i += 256) {
        int2 e = ent[i];
        int dl = e.x >> 16;
        int p = atomicAdd(&off[dl], 1);
        ent2[p] = make_int2(e.x & 0xFFFF, e.y);
    }
    __syncthreads();
    // wsum per node from sorted runs (no atomics): 4 lanes per node
    {
        int nl = t >> 2, l = t & 3;
        int beg = excl[nl];
        int end = beg + hist[nl];
        float s = 0.f;
        for (int j = beg + l; j < end; j += 4) s += __int_as_float(ent2[j].y);
        s += __shfl_xor(s, 1, 64);
        s += __shfl_xor(s, 2, 64);
        if (l == 0) sdinv[nl] = rsqrtf(1.0f + s);
    }
    __syncthreads();
    int n0 = b * BIN_W;
    // coalesced write of sorted segment
    int2* s2 = seg2 + (size_t)b * BCAP;
    for (int i = t; i < c; i += 256) s2[i] = ent2[i];
    // rowinfo + dinv
    if (t < BIN_W && n0 + t < N_NODES) {
        dinv[n0 + t] = sdinv[t];
        rowinfo[n0 + t] = make_int2(b * BCAP + excl[t], hist[t]);
    }
    // y = dinv * x (padded rows)
    for (int i = t; i < BIN_W * P_PER; i += 256) {
        int nl = i / P_PER, p = i - nl * P_PER;
        int n = n0 + nl;
        if (n < N_NODES) y[(size_t)n * Y_STR + p] = sdinv[nl] * x[(size_t)n * P_PER + p];
    }
}

// k4: gather + fused epilogue. 16 lanes/node, contiguous runs, zero atomics.
//  acc[p] = sum_run w*y[s,p];  a = dinv[n]*(acc + y[n])
//  out[n] = bout + sum_k relu( sum_p probs[p]*sigmoid(-(a*uz+cz))*tanh(a*uh+ch) )*Wout[k]
__global__ __launch_bounds__(256) void gather_finalize_kernel(const int2* __restrict__ seg2,
                                                              const int2* __restrict__ rowinfo,
                                                              const float* __restrict__ y,
                                                              const float* __restrict__ dinv,
                                                              const float* __restrict__ uz,
                                                              const float* __restrict__ cz,
                                                              const float* __restrict__ uh,
                                                              const float* __restrict__ ch,
                                                              const float* __restrict__ probs,
                                                              const float* __restrict__ Wout,
                                                              const float* __restrict__ bout,
                                                              float* __restrict__ out) {
    __shared__ float s_uz[HID], s_cz[HID], s_uh[HID], s_ch[HID], s_wo[HID];
    __shared__ float s_pr[P_PER];
    int t = threadIdx.x;
    if (t < HID) {
        s_uz[t] = uz[t]; s_cz[t] = cz[t];
        s_uh[t] = uh[t]; s_ch[t] = ch[t];
        s_wo[t] = Wout[t];
    }
    if (t < P_PER) s_pr[t] = probs[t];
    __syncthreads();

    int tid = blockIdx.x * blockDim.x + t;
    int n = tid >> 4;
    int l = tid & 15;
    if (n >= N_NODES) return;

    int2 ri = rowinfo[n];              // (start, len)
    float acc[P_PER];
#pragma unroll
    for (int p = 0; p < P_PER; ++p) acc[p] = 0.f;
    int end = ri.x + ri.y;
    for (int j = ri.x + l; j < end; j += 16) {
        int2 e = seg2[j];
        float wt = __int_as_float(e.y);
        const float4* yr = (const float4*)(y + (size_t)e.x * Y_STR);
        float4 y0 = yr[0], y1 = yr[1], y2 = yr[2];
        acc[0]  += wt * y0.x;  acc[1]  += wt * y0.y;
        acc[2]  += wt * y0.z;  acc[3]  += wt * y0.w;
        acc[4]  += wt * y1.x;  acc[5]  += wt * y1.y;
        acc[6]  += wt * y1.z;  acc[7]  += wt * y1.w;
        acc[8]  += wt * y2.x;  acc[9]  += wt * y2.y;
        acc[10] += wt * y2.z;  acc[11] += wt * y2.w;
    }
    // xor-reduce over 16-lane group; all lanes end with full sums
#pragma unroll
    for (int off = 8; off >= 1; off >>= 1) {
#pragma unroll
        for (int p = 0; p < P_PER; ++p) acc[p] += __shfl_xor(acc[p], off, 64);
    }
    {
        float dn = dinv[n];
        const float4* yr = (const float4*)(y + (size_t)n * Y_STR);
        float4 y0 = yr[0], y1 = yr[1], y2 = yr[2];
        acc[0]  = dn * (acc[0]  + y0.x);  acc[1]  = dn * (acc[1]  + y0.y);
        acc[2]  = dn * (acc[2]  + y0.z);  acc[3]  = dn * (acc[3]  + y0.w);
        acc[4]  = dn * (acc[4]  + y1.x);  acc[5]  = dn * (acc[5]  + y1.y);
        acc[6]  = dn * (acc[6]  + y1.z);  acc[7]  = dn * (acc[7]  + y1.w);
        acc[8]  = dn * (acc[8]  + y2.x);  acc[9]  = dn * (acc[9]  + y2.y);
        acc[10] = dn * (acc[10] + y2.z);  acc[11] = dn * (acc[11] + y2.w);
    }
    float rk = 0.f;
    for (int k = l; k < HID; k += 16) {     // 7 or 6 iterations per lane
        float uzk = s_uz[k], czk = s_cz[k], uhk = s_uh[k], chk = s_ch[k];
        float a2 = 0.f;
#pragma unroll
        for (int p = 0; p < P_PER; ++p) {
            float av = acc[p];
            float vz = fminf(fmaxf(av * uzk + czk, -30.f), 30.f);
            float vh = fminf(fmaxf(av * uhk + chk, -15.f), 15.f);
            float ez  = __expf(vz);
            float e2h = __expf(2.0f * vh);
            float term = (e2h - 1.0f) / ((1.0f + ez) * (e2h + 1.0f));  // sigmoid(-vz)*tanh(vh)
            a2 += s_pr[p] * term;
        }
        rk += fmaxf(a2, 0.0f) * s_wo[k];
    }
#pragma unroll
    for (int off = 8; off >= 1; off >>= 1) rk += __shfl_xor(rk, off, 64);
    if (l == 0) out[n] = rk + bout[0];
}

extern "C" void kernel_launch(void* const* d_in, const int* in_sizes, int n_in,
                              void* d_out, int out_size, void* d_ws, size_t ws_size,
                              hipStream_t stream) {
    const float* x   = (const float*)d_in[0];
    const int*   ei  = (const int*)d_in[1];
    const float* ew  = (const float*)d_in[2];
    const float* Wz  = (const float*)d_in[3];
    const float* bz  = (const float*)d_in[4];
    // d_in[5], d_in[6]: W_r, b_r — dead (H0 = 0)
    const float* Wh  = (const float*)d_in[7];
    const float* bh  = (const float*)d_in[8];
    const float* Wlz = (const float*)d_in[9];
    const float* blz = (const float*)d_in[10];
    // d_in[11], d_in[12]: Wl_r, bl_r — dead
    const float* Wlh = (const float*)d_in[13];
    const float* blh = (const float*)d_in[14];
    const float* att = (const float*)d_in[15];
    const float* Wout = (const float*)d_in[16];
    const float* bout = (const float*)d_in[17];
    float* out = (float*)d_out;

    float* ws      = (float*)d_ws;
    float* dinv    = ws + OFF_DINV;
    float* uz      = ws + OFF_UZ;
    float* cz      = ws + OFF_CZ;
    float* uh      = ws + OFF_UH;
    float* ch      = ws + OFF_CH;
    float* probs   = ws + OFF_PROBS;
    int*   cur     = (int*)(ws + OFF_CUR);
    float* y       = ws + OFF_Y;
    int2*  seg     = (int2*)(ws + OFF_SEG);
    int2*  seg2    = (int2*)(ws + OFF_SEG2);
    int2*  rowinfo = (int2*)(ws + OFF_ROW);

    hipMemsetAsync(cur, 0, (size_t)NB * CUR_STR * sizeof(int), stream);
    hipLaunchKernelGGL(precompute_kernel, dim3(1), dim3(128), 0, stream,
                       Wz, bz, Wh, bh, Wlz, blz, Wlh, blh, att, uz, cz, uh, ch, probs);
    hipLaunchKernelGGL(partition_kernel, dim3(NBLK2), dim3(256), 0, stream,
                       ei, ew, cur, seg);
    hipLaunchKernelGGL(binsort_kernel, dim3(NB), dim3(256), 0, stream,
                       seg, cur, x, dinv, y, seg2, rowinfo);
    hipLaunchKernelGGL(gather_finalize_kernel, dim3((N_NODES * 16 + 255) / 256), dim3(256), 0, stream,
                       seg2, rowinfo, y, dinv, uz, cz, uh, ch, probs, Wout, bout, out);
}